// Round 7
// baseline (164.744 us; speedup 1.0000x reference)
//
#include <hip/hip_runtime.h>

typedef float  f32x4  __attribute__((ext_vector_type(4)));
typedef __bf16 bf16x8 __attribute__((ext_vector_type(8)));
typedef unsigned short u16x8 __attribute__((ext_vector_type(8)));

#define NL2E (-1.44269504088896f)   // -log2(e)
#define TL2E ( 2.88539008177793f)   // 2*log2(e)

__device__ __forceinline__ float rcpf(float x) { return __builtin_amdgcn_rcpf(x); }
__device__ __forceinline__ float ex2(float x)  { return __builtin_amdgcn_exp2f(x); }

// layer-2 cell (scalar), pre-scaled args
__device__ __forceinline__ float cell_update(float zi, float zf, float zg, float zo, float& c) {
    const float Ei = ex2(zi), Ef = ex2(zf), Eg = ex2(zg), Eo = ex2(zo);
    const float ig = (Eg - 1.0f) * rcpf((1.0f + Ei) * (1.0f + Eg));
    const float fv = rcpf(1.0f + Ef);
    c = __builtin_fmaf(fv, c, ig);
    const float zc = fminf(fmaxf(TL2E * c, -60.0f), 60.0f);
    const float Ec = ex2(zc);
    return (Ec - 1.0f) * rcpf((1.0f + Eo) * (1.0f + Ec));   // o*tanh(c)
}

// 16 batches/WG, 4 waves, grid 256 (1 WG/CU), one barrier per timestep.
// Wave w owns N-tiles {w,w+4,w+8,w+12} -> lane (q,hi) holds all 4 gates of
// hidden he=16w+q for batches 4hi+j in its MFMA accs.
// This round: a2 (x-frag) carried in regs + a2-first MFMA order; wave-1
// layer-2 moved into its MFMA shadow; staged exp2 elementwise.
__global__ __launch_bounds__(256, 1) void lstm_fused(
    const float* __restrict__ x,      // [4096][256][16]
    const float* __restrict__ w_ih1,  // [256][16]
    const float* __restrict__ w_hh1,  // [256][64]
    const float* __restrict__ b_ih1, const float* __restrict__ b_hh1,
    const float* __restrict__ w_ih2,  // [4][64]
    const float* __restrict__ w_hh2,  // [4]
    const float* __restrict__ b_ih2, const float* __restrict__ b_hh2,
    const float* __restrict__ fc_w, const float* __restrict__ fc_b,
    float* __restrict__ out)          // [4096][256]
{
    __shared__ unsigned short A_h[2 * 16 * 64];        // 4KB dbuf h1 bf16 [buf][b][he], ^((b&7)<<4)
    __shared__ unsigned short Xc[2 * 16 * 16 * 32];    // 32KB dbuf x bf16 [buf][b][tt][k]
    __shared__ float Pre2[2][64];                      // dbuf layer-2 preacts [buf][b*4+g]
    __shared__ float Ybuf[16][16];                     // [b][tt] (wave-1 private)

    const int tid = threadIdx.x;
    const int wv  = tid >> 6;
    const int l   = tid & 63;
    const int q   = l & 15;
    const int hi  = l >> 4;
    const int b0  = blockIdx.x << 4;
    const int he  = (wv << 4) + q;
    const int sw  = (q & 7) << 4;

    ((u16x8*)A_h)[tid] = (u16x8){0,0,0,0,0,0,0,0};

    // ---- B fragments, pre-scaled so MFMA acc is directly the exp2 argument ----
    bf16x8 Bf[4][3];
    #pragma unroll
    for (int g = 0; g < 4; ++g) {
        const float sc = (g == 2) ? TL2E : NL2E;
        const int n = (g << 6) + (wv << 4) + q;
        #pragma unroll
        for (int ks = 0; ks < 3; ++ks) {
            bf16x8 tmp;
            #pragma unroll
            for (int j = 0; j < 8; ++j) {
                const int k = ks * 32 + hi * 8 + j;
                float v = 0.f;
                if (k < 64)      v = w_hh1[n * 64 + k];
                else if (k < 80) v = w_ih1[n * 16 + (k - 64)];
                tmp[j] = (__bf16)(sc * v);
            }
            Bf[g][ks] = tmp;
        }
    }
    bf16x8 B2[2];                                      // layer-2 input proj (wave 3)
    {
        const float sc2 = (q == 2) ? TL2E : NL2E;
        #pragma unroll
        for (int ks = 0; ks < 2; ++ks) {
            bf16x8 tmp;
            #pragma unroll
            for (int j = 0; j < 8; ++j) {
                const int k = ks * 32 + hi * 8 + j;
                const float v = (q < 4) ? w_ih2[q * 64 + k] : 0.f;
                tmp[j] = (__bf16)(sc2 * v);
            }
            B2[ks] = tmp;
        }
    }

    float accb[4];
    #pragma unroll
    for (int g = 0; g < 4; ++g) {
        const float sc = (g == 2) ? TL2E : NL2E;
        accb[g] = sc * (b_ih1[(g << 6) + he] + b_hh1[(g << 6) + he]);
    }

    const float w2si = NL2E * w_hh2[0], w2sf = NL2E * w_hh2[1];
    const float w2sg = TL2E * w_hh2[2], w2so = NL2E * w_hh2[3];
    const float nb2i = NL2E * (b_ih2[0] + b_hh2[0]);
    const float nb2f = NL2E * (b_ih2[1] + b_hh2[1]);
    const float tb2g = TL2E * (b_ih2[2] + b_hh2[2]);
    const float nb2o = NL2E * (b_ih2[3] + b_hh2[3]);
    const float fcw = fc_w[0], fcb = fc_b[0];

    // ---- x staging ----
    const int bx = tid >> 4, part = tid & 15;
    const int swx = (bx & 7) << 4;
    const unsigned xo0 = (unsigned)(bx * 1024 + (((part << 6) +  0) ^ swx));
    const unsigned xo1 = (unsigned)(bx * 1024 + (((part << 6) + 16) ^ swx));
    const unsigned xo2 = (unsigned)(bx * 1024 + (((part << 6) + 32) ^ swx));
    const unsigned xo3 = (unsigned)(bx * 1024 + (((part << 6) + 48) ^ swx));
    const float* xrow = x + (size_t)(b0 + bx) * 4096 + part * 16;

    f32x4 xq0, xq1, xq2, xq3;
    auto stage_x = [&](int bufoff) {
        bf16x8 lo, hw;
        #pragma unroll
        for (int j = 0; j < 4; ++j) {
            lo[j] = (__bf16)xq0[j]; lo[4 + j] = (__bf16)xq1[j];
            hw[j] = (__bf16)xq2[j]; hw[4 + j] = (__bf16)xq3[j];
        }
        const u16x8 z = {0,0,0,0,0,0,0,0};
        char* base = (char*)Xc + bufoff;
        *(u16x8*)(base + xo0) = __builtin_bit_cast(u16x8, lo);
        *(u16x8*)(base + xo1) = __builtin_bit_cast(u16x8, hw);
        *(u16x8*)(base + xo2) = z;
        *(u16x8*)(base + xo3) = z;
    };

    xq0 = ((const f32x4*)xrow)[0]; xq1 = ((const f32x4*)xrow)[1];
    xq2 = ((const f32x4*)xrow)[2]; xq3 = ((const f32x4*)xrow)[3];
    stage_x(0);
    {
        const float* p = xrow + 256;
        xq0 = ((const f32x4*)p)[0]; xq1 = ((const f32x4*)p)[1];
        xq2 = ((const f32x4*)p)[2]; xq3 = ((const f32x4*)p)[3];
    }

    const unsigned ar0 = (unsigned)((q * 128 +      hi * 16) ^ sw);
    const unsigned ar1 = (unsigned)((q * 128 + 64 + hi * 16) ^ sw);
    unsigned awb[4];
    #pragma unroll
    for (int j = 0; j < 4; ++j) {
        const int b = (hi << 2) + j;
        awb[j] = (unsigned)(b * 128 + ((he * 2) ^ ((b & 7) << 4)));
    }

    float c1[4] = {0.f, 0.f, 0.f, 0.f};
    float h2 = 0.f, c2 = 0.f;

    __syncthreads();

    // x-fragment for t=0 carried in regs
    u16x8 ra2cur = *(const u16x8*)((const char*)Xc + ((q * 1024 + (hi << 4)) ^ sw));

    #pragma unroll 2
    for (int t = 0; t < 256; ++t) {
        const int tt = t & 15;
        if (tt == 0 && t + 16 < 256) {
            stage_x(((((t >> 4) + 1) & 1)) << 14);
            if (t + 32 < 256) {
                const float* p = xrow + (t + 32) * 16;
                xq0 = ((const f32x4*)p)[0]; xq1 = ((const f32x4*)p)[1];
                xq2 = ((const f32x4*)p)[2]; xq3 = ((const f32x4*)p)[3];
            }
        }

        // h_{t-1} fragment reads (the only loads the MFMA must wait on)
        const int rb = ((t + 1) & 1) << 11;
        const u16x8 ra0 = *(const u16x8*)((const char*)A_h + rb + ar0);
        const u16x8 ra1 = *(const u16x8*)((const char*)A_h + rb + ar1);
        // pre-read x-fragment for t+1 (chunk visibility guaranteed: its staging
        // barrier passed >=1 step ago for all t)
        const int tn = (t < 255) ? t + 1 : t;
        const u16x8 ra2nxt = *(const u16x8*)((const char*)Xc + (((tn >> 4) & 1) << 14)
                               + ((q * 1024 + ((tn & 15) << 6) + (hi << 4)) ^ sw));
        // wave-1: issue layer-2 preact read early (used later, in MFMA shadow)
        f32x4 p2;
        if (wv == 1) p2 = *(const f32x4*)&Pre2[(t + 1) & 1][(l & 15) << 2];

        // ---- MFMA: a2 (regs, no wait) first, then a0, a1 ----
        const bf16x8 a2 = __builtin_bit_cast(bf16x8, ra2cur);
        f32x4 g0 = {accb[0], accb[0], accb[0], accb[0]};
        f32x4 g1 = {accb[1], accb[1], accb[1], accb[1]};
        f32x4 g2 = {accb[2], accb[2], accb[2], accb[2]};
        f32x4 g3 = {accb[3], accb[3], accb[3], accb[3]};
        g0 = __builtin_amdgcn_mfma_f32_16x16x32_bf16(a2, Bf[0][2], g0, 0, 0, 0);
        g1 = __builtin_amdgcn_mfma_f32_16x16x32_bf16(a2, Bf[1][2], g1, 0, 0, 0);
        g2 = __builtin_amdgcn_mfma_f32_16x16x32_bf16(a2, Bf[2][2], g2, 0, 0, 0);
        g3 = __builtin_amdgcn_mfma_f32_16x16x32_bf16(a2, Bf[3][2], g3, 0, 0, 0);
        const bf16x8 a0 = __builtin_bit_cast(bf16x8, ra0);
        g0 = __builtin_amdgcn_mfma_f32_16x16x32_bf16(a0, Bf[0][0], g0, 0, 0, 0);
        g1 = __builtin_amdgcn_mfma_f32_16x16x32_bf16(a0, Bf[1][0], g1, 0, 0, 0);
        g2 = __builtin_amdgcn_mfma_f32_16x16x32_bf16(a0, Bf[2][0], g2, 0, 0, 0);
        g3 = __builtin_amdgcn_mfma_f32_16x16x32_bf16(a0, Bf[3][0], g3, 0, 0, 0);
        const bf16x8 a1 = __builtin_bit_cast(bf16x8, ra1);
        g0 = __builtin_amdgcn_mfma_f32_16x16x32_bf16(a1, Bf[0][1], g0, 0, 0, 0);
        g1 = __builtin_amdgcn_mfma_f32_16x16x32_bf16(a1, Bf[1][1], g1, 0, 0, 0);
        g2 = __builtin_amdgcn_mfma_f32_16x16x32_bf16(a1, Bf[2][1], g2, 0, 0, 0);
        g3 = __builtin_amdgcn_mfma_f32_16x16x32_bf16(a1, Bf[3][1], g3, 0, 0, 0);

        if (wv == 3) {   // layer-2 input projection of h_{t-1} -> Pre2[t&1]
            f32x4 p4 = {0.f, 0.f, 0.f, 0.f};
            p4 = __builtin_amdgcn_mfma_f32_16x16x32_bf16(a0, B2[0], p4, 0, 0, 0);
            p4 = __builtin_amdgcn_mfma_f32_16x16x32_bf16(a1, B2[1], p4, 0, 0, 0);
            if (q < 4) {
                #pragma unroll
                for (int r = 0; r < 4; ++r) Pre2[t & 1][((hi << 2) + r) * 4 + q] = p4[r];
            }
        }

        // ---- wave-1 layer-2 + FC, in the main-MFMA pipe shadow ----
        if (wv == 1 && t >= 2) {
            const int s = t - 2;
            if (l < 16) {
                const float zi = p2[0] + __builtin_fmaf(w2si, h2, nb2i);
                const float zf = p2[1] + __builtin_fmaf(w2sf, h2, nb2f);
                const float zg = p2[2] + __builtin_fmaf(w2sg, h2, tb2g);
                const float zo = p2[3] + __builtin_fmaf(w2so, h2, nb2o);
                h2 = cell_update(zi, zf, zg, zo, c2);
                Ybuf[l][s & 15] = __builtin_fmaf(fcw, h2, fcb);
            }
            if ((s & 15) == 15) {
                float* op = out + (size_t)(b0 + (l >> 2)) * 256 + (s - 15) + ((l & 3) << 2);
                *(f32x4*)op = *(const f32x4*)&Ybuf[l >> 2][(l & 3) << 2];
            }
        }

        // ---- staged elementwise: exp2 in gate order (overlaps MFMA tail) ----
        float Ei[4], Ef[4], Eg[4], Eo[4];
        #pragma unroll
        for (int j = 0; j < 4; ++j) Ei[j] = ex2(g0[j]);
        #pragma unroll
        for (int j = 0; j < 4; ++j) Ef[j] = ex2(g1[j]);
        #pragma unroll
        for (int j = 0; j < 4; ++j) Eg[j] = ex2(g2[j]);
        #pragma unroll
        for (int j = 0; j < 4; ++j) Eo[j] = ex2(g3[j]);
        char* AW = (char*)A_h + ((t & 1) << 11);
        #pragma unroll
        for (int j = 0; j < 4; ++j) {
            const float ig = (Eg[j] - 1.0f) * rcpf((1.0f + Ei[j]) * (1.0f + Eg[j]));
            const float fv = rcpf(1.0f + Ef[j]);
            c1[j] = __builtin_fmaf(fv, c1[j], ig);
            const float zc = fminf(fmaxf(TL2E * c1[j], -60.0f), 60.0f);
            const float Ec = ex2(zc);
            const float hv = (Ec - 1.0f) * rcpf((1.0f + Eo[j]) * (1.0f + Ec));
            *(unsigned short*)(AW + awb[j]) = __builtin_bit_cast(unsigned short, (__bf16)hv);
        }

        ra2cur = ra2nxt;
        __syncthreads();
    }

    // ---- epilogue: layer-2 steps s=254 (Pre2[1]) and s=255 (fresh proj h_255) ----
    if (wv == 3) {
        const u16x8 ra0 = *(const u16x8*)((const char*)A_h + 2048 + ar0);
        const u16x8 ra1 = *(const u16x8*)((const char*)A_h + 2048 + ar1);
        f32x4 p4 = {0.f, 0.f, 0.f, 0.f};
        p4 = __builtin_amdgcn_mfma_f32_16x16x32_bf16(__builtin_bit_cast(bf16x8, ra0), B2[0], p4, 0, 0, 0);
        p4 = __builtin_amdgcn_mfma_f32_16x16x32_bf16(__builtin_bit_cast(bf16x8, ra1), B2[1], p4, 0, 0, 0);
        if (q < 4) {
            #pragma unroll
            for (int r = 0; r < 4; ++r) Pre2[0][((hi << 2) + r) * 4 + q] = p4[r];
        }
    }
    __syncthreads();
    if (wv == 1) {
        if (l < 16) {
            #pragma unroll
            for (int e = 0; e < 2; ++e) {   // e=0 -> s=254 (Pre2[1]), e=1 -> s=255 (Pre2[0])
                const f32x4 p2 = *(const f32x4*)&Pre2[1 - e][l << 2];
                const float zi = p2[0] + __builtin_fmaf(w2si, h2, nb2i);
                const float zf = p2[1] + __builtin_fmaf(w2sf, h2, nb2f);
                const float zg = p2[2] + __builtin_fmaf(w2sg, h2, tb2g);
                const float zo = p2[3] + __builtin_fmaf(w2so, h2, nb2o);
                h2 = cell_update(zi, zf, zg, zo, c2);
                Ybuf[l][14 + e] = __builtin_fmaf(fcw, h2, fcb);
            }
        }
        float* op = out + (size_t)(b0 + (l >> 2)) * 256 + 240 + ((l & 3) << 2);
        *(f32x4*)op = *(const f32x4*)&Ybuf[l >> 2][(l & 3) << 2];
    }
}

extern "C" void kernel_launch(void* const* d_in, const int* in_sizes, int n_in,
                              void* d_out, int out_size, void* d_ws, size_t ws_size,
                              hipStream_t stream) {
    (void)in_sizes; (void)n_in; (void)out_size; (void)d_ws; (void)ws_size;
    const float* x     = (const float*)d_in[0];
    const float* w_ih1 = (const float*)d_in[1];
    const float* w_hh1 = (const float*)d_in[2];
    const float* b_ih1 = (const float*)d_in[3];
    const float* b_hh1 = (const float*)d_in[4];
    const float* w_ih2 = (const float*)d_in[5];
    const float* w_hh2 = (const float*)d_in[6];
    const float* b_ih2 = (const float*)d_in[7];
    const float* b_hh2 = (const float*)d_in[8];
    const float* fc_w  = (const float*)d_in[9];
    const float* fc_b  = (const float*)d_in[10];
    lstm_fused<<<dim3(256), dim3(256), 0, stream>>>(
        x, w_ih1, w_hh1, b_ih1, b_hh1, w_ih2, w_hh2, b_ih2, b_hh2, fc_w, fc_b,
        (float*)d_out);
}